// Round 1
// baseline (286.256 us; speedup 1.0000x reference)
//
#include <hip/hip_runtime.h>
#include <math.h>

#define NF 26
#define VOCAB 100000
#define EMB 16
#define BATCH 16384
#define KD 16
#define NTOT (NF * EMB)   // 416

// ---------------------------------------------------------------------------
// Pre-kernel: wv[n] = { W[n], sum_k v[n,k]^2 }  (416 float2 into d_ws)
// sum_of_square collapses to a single dot-product with vsq:
//   sum_k sum_n e_n^2 v[n,k]^2 = sum_n e_n^2 * vsq_n
// ---------------------------------------------------------------------------
__global__ void precompute_wv(const float* __restrict__ W,
                              const float* __restrict__ v,
                              float2* __restrict__ wv) {
    int n = blockIdx.x * blockDim.x + threadIdx.x;
    if (n < NTOT) {
        const float* vr = v + n * KD;
        float s = 0.f;
#pragma unroll
        for (int k = 0; k < KD; ++k) s = fmaf(vr[k], vr[k], s);
        wv[n] = make_float2(W[n], s);
    }
}

// ---------------------------------------------------------------------------
// Main kernel: one thread per batch row. 256 blocks x 64 threads = 1 wave/CU.
// v and wv reads are wave-uniform -> scalar (s_load) path, constant cache.
// Embedding gathers double-buffered across the field loop to hide HBM latency
// (only 1 wave/SIMD, so ILP must hide it).
// ---------------------------------------------------------------------------
__device__ __forceinline__ void comp4(float4 ev4, int nbase,
                                      const float* __restrict__ v,
                                      const float2* __restrict__ wv,
                                      float& lin, float& sos, float* xv) {
    float e[4] = {ev4.x, ev4.y, ev4.z, ev4.w};
#pragma unroll
    for (int j = 0; j < 4; ++j) {
        const float ev = e[j];
        const float2 w2 = wv[nbase + j];          // uniform -> s_load
        lin = fmaf(ev, w2.x, lin);
        sos = fmaf(ev * ev, w2.y, sos);
        const float* vr = v + (nbase + j) * KD;   // uniform -> s_load_dwordx16
#pragma unroll
        for (int k = 0; k < KD; ++k)
            xv[k] = fmaf(ev, vr[k], xv[k]);
    }
}

__device__ __forceinline__ void load_field(float4* dst,
                                           const float* __restrict__ tables,
                                           int f, int idx) {
    const float4* er =
        (const float4*)(tables + ((size_t)f * VOCAB + (size_t)idx) * EMB);
    dst[0] = er[0];
    dst[1] = er[1];
    dst[2] = er[2];
    dst[3] = er[3];
}

__global__ __launch_bounds__(64, 1) void fm_kernel(
    const int* __restrict__ X, const float* __restrict__ tables,
    const float* __restrict__ bptr, const float* __restrict__ v,
    const float2* __restrict__ wv, float* __restrict__ out) {
    const int row = blockIdx.x * 64 + threadIdx.x;

    // Load this row's 26 indices. Row stride = 104 B -> 8 B aligned, use int2.
    int idx[NF];
    {
        const int2* xr = (const int2*)(X + row * NF);
#pragma unroll
        for (int i = 0; i < NF / 2; ++i) {
            int2 t = xr[i];
            idx[2 * i + 0] = t.x;
            idx[2 * i + 1] = t.y;
        }
    }

    float xv[KD];
#pragma unroll
    for (int k = 0; k < KD; ++k) xv[k] = 0.f;
    float lin = 0.f, sos = 0.f;

    // Ping-pong double buffer over the 26 fields (26 is even).
    float4 A[4], B[4];
    load_field(A, tables, 0, idx[0]);
#pragma unroll 1
    for (int f = 0; f < NF; f += 2) {
        load_field(B, tables, f + 1, idx[f + 1]);
#pragma unroll
        for (int q = 0; q < 4; ++q)
            comp4(A[q], (f)*EMB + 4 * q, v, wv, lin, sos, xv);
        if (f + 2 < NF) load_field(A, tables, f + 2, idx[f + 2]);
#pragma unroll
        for (int q = 0; q < 4; ++q)
            comp4(B[q], (f + 1) * EMB + 4 * q, v, wv, lin, sos, xv);
    }

    float ss = 0.f;
#pragma unroll
    for (int k = 0; k < KD; ++k) ss = fmaf(xv[k], xv[k], ss);

    const float z = lin + bptr[0] + 0.5f * (ss - sos);
    out[row] = 1.0f / (1.0f + expf(-z));
}

// ---------------------------------------------------------------------------
// Inputs (setup_inputs order): X[int32 16384x26], tables[f32 26x100000x16],
// W[f32 416x1], b[f32 1], v[f32 416x16].  Output: f32 [16384].
// ---------------------------------------------------------------------------
extern "C" void kernel_launch(void* const* d_in, const int* in_sizes, int n_in,
                              void* d_out, int out_size, void* d_ws,
                              size_t ws_size, hipStream_t stream) {
    const int* X = (const int*)d_in[0];
    const float* tables = (const float*)d_in[1];
    const float* W = (const float*)d_in[2];
    const float* b = (const float*)d_in[3];
    const float* v = (const float*)d_in[4];
    float* out = (float*)d_out;
    float2* wv = (float2*)d_ws;  // 416 * 8 B = 3328 B scratch

    precompute_wv<<<2, 256, 0, stream>>>(W, v, wv);
    fm_kernel<<<BATCH / 64, 64, 0, stream>>>(X, tables, b, v, wv, out);
}

// Round 2
// 227.686 us; speedup vs baseline: 1.2572x; 1.2572x over previous
//
#include <hip/hip_runtime.h>
#include <math.h>

#define NF 26
#define VOCAB 100000
#define EMB 16
#define BATCH 16384
#define KD 16
#define NTOT (NF * EMB)  // 416
#define NP 420           // padded vT inner stride: bank start = 4k%32 -> only 2-way (free)

// One block = 256 threads = 16 row-groups x 16 lanes. Lane k of a group owns
// factor dim k of that row. grid = 16384/16 = 1024 blocks = 4 blocks/CU,
// 16 waves/CU (vs round-1's 1 wave/CU -- the latency killer).
__global__ __launch_bounds__(256, 4) void fm_kernel(
    const int* __restrict__ X, const float* __restrict__ tables,
    const float* __restrict__ W, const float* __restrict__ bptr,
    const float* __restrict__ v, float* __restrict__ out) {
    __shared__ float vT[KD][NP];   // 26880 B: v transposed, padded
    __shared__ float2 wvs[NTOT];   // 3328 B: {W[n], sum_k v[n,k]^2}

    const int tid = threadIdx.x;

    // Stage v -> vT (coalesced reads; LDS writes are 2-way = free).
    for (int t = tid; t < NTOT * KD; t += 256) {
        int n = t >> 4, kk = t & 15;
        vT[kk][n] = v[t];
    }
    // wv: sum_of_square collapses to e_n^2 dot vsq_n.
    for (int n = tid; n < NTOT; n += 256) {
        const float* vr = v + n * KD;
        float s = 0.f;
#pragma unroll
        for (int k2 = 0; k2 < KD; ++k2) s = fmaf(vr[k2], vr[k2], s);
        wvs[n] = make_float2(W[n], s);
    }
    __syncthreads();

    const int g = tid >> 4;
    const int k = tid & 15;
    const int row = blockIdx.x * 16 + g;

    // Row indices: 16-way broadcast load (8 B aligned: 26*4 = 104 B stride).
    int idx[NF];
    {
        const int2* xr = (const int2*)(X + row * NF);
#pragma unroll
        for (int i = 0; i < NF / 2; ++i) {
            int2 t2 = xr[i];
            idx[2 * i] = t2.x;
            idx[2 * i + 1] = t2.y;
        }
    }

    float xv0 = 0.f, xv1 = 0.f;  // two chains for ILP
    float lin = 0.f, sos = 0.f;

    float4 A0, A1, A2, A3, B0, B1, B2, B3;
    float ekA, ekB;
    {
        const float* er = tables + (size_t)idx[0] * EMB;  // f = 0
        const float4* e4 = (const float4*)er;
        A0 = e4[0]; A1 = e4[1]; A2 = e4[2]; A3 = e4[3];
        ekA = er[k];
    }

#pragma unroll 2
    for (int f = 0; f < NF; ++f) {
        // Prefetch next field's embedding row (broadcast across the 16 lanes).
        if (f + 1 < NF) {
            const float* er =
                tables + ((size_t)(f + 1) * VOCAB + (size_t)idx[f + 1]) * EMB;
            const float4* e4 = (const float4*)er;
            B0 = e4[0]; B1 = e4[1]; B2 = e4[2]; B3 = e4[3];
            ekB = er[k];
        }

        const int nb = f * EMB;
        // Lane k's v-column slice: 4x ds_read_b128, 16 B aligned.
        const float4* vr = (const float4*)&vT[k][nb];
        float4 v0 = vr[0], v1 = vr[1], v2 = vr[2], v3 = vr[3];

        xv0 = fmaf(A0.x, v0.x, xv0);
        xv0 = fmaf(A0.y, v0.y, xv0);
        xv0 = fmaf(A0.z, v0.z, xv0);
        xv0 = fmaf(A0.w, v0.w, xv0);
        xv0 = fmaf(A1.x, v1.x, xv0);
        xv0 = fmaf(A1.y, v1.y, xv0);
        xv0 = fmaf(A1.z, v1.z, xv0);
        xv0 = fmaf(A1.w, v1.w, xv0);
        xv1 = fmaf(A2.x, v2.x, xv1);
        xv1 = fmaf(A2.y, v2.y, xv1);
        xv1 = fmaf(A2.z, v2.z, xv1);
        xv1 = fmaf(A2.w, v2.w, xv1);
        xv1 = fmaf(A3.x, v3.x, xv1);
        xv1 = fmaf(A3.y, v3.y, xv1);
        xv1 = fmaf(A3.z, v3.z, xv1);
        xv1 = fmaf(A3.w, v3.w, xv1);

        // lin/sos partials: lane k handles the n = f*16+k slice.
        float2 w2 = wvs[nb + k];
        lin = fmaf(ekA, w2.x, lin);
        sos = fmaf(ekA * ekA, w2.y, sos);

        A0 = B0; A1 = B1; A2 = B2; A3 = B3; ekA = ekB;
    }

    const float xv = xv0 + xv1;
    // z = b + sum_k [ lin_k + 0.5*(xv_k^2 - sos_k) ]
    float p = lin + 0.5f * (xv * xv - sos);
    p += __shfl_xor(p, 1, 16);
    p += __shfl_xor(p, 2, 16);
    p += __shfl_xor(p, 4, 16);
    p += __shfl_xor(p, 8, 16);

    if (k == 0) {
        const float z = p + bptr[0];
        out[row] = 1.0f / (1.0f + __expf(-z));
    }
}

// Inputs: X[int32 16384x26], tables[f32 26x100000x16], W[f32 416x1],
// b[f32 1], v[f32 416x16]. Output: f32 [16384].
extern "C" void kernel_launch(void* const* d_in, const int* in_sizes, int n_in,
                              void* d_out, int out_size, void* d_ws,
                              size_t ws_size, hipStream_t stream) {
    const int* X = (const int*)d_in[0];
    const float* tables = (const float*)d_in[1];
    const float* W = (const float*)d_in[2];
    const float* b = (const float*)d_in[3];
    const float* v = (const float*)d_in[4];
    float* out = (float*)d_out;

    fm_kernel<<<BATCH / 16, 256, 0, stream>>>(X, tables, W, b, v, out);
}

// Round 3
// 219.992 us; speedup vs baseline: 1.3012x; 1.0350x over previous
//
#include <hip/hip_runtime.h>
#include <math.h>

#define NF 26
#define VOCAB 100000
#define EMB 16
#define BATCH 16384
#define KD 16
#define NTOT (NF * EMB)  // 416
#define VSTRIDE 20       // padded LDS row stride (floats): 16B-aligned, 2-way bank alias = free

// Block = 256 threads = 16 row-groups x 16 lanes. Lane j of a group owns
// embedding ELEMENT j: its 26 gather loads (one per field) are independent
// and issued upfront -> MLP depth 26 (round 2 was depth 2 -> latency-bound).
// v rows come from LDS (natural layout, padded); xv reduced with a 16-lane
// vector butterfly.
__global__ __launch_bounds__(256, 4) void fm_kernel(
    const int* __restrict__ X, const float* __restrict__ tables,
    const float* __restrict__ W, const float* __restrict__ bptr,
    const float* __restrict__ v, float* __restrict__ out) {
    __shared__ float vL[NTOT * VSTRIDE];  // 33280 B
    __shared__ float2 wvs[NTOT];          // 3328 B: {W[n], sum_k v[n,k]^2}

    const int tid = threadIdx.x;

    // Stage v into padded LDS rows (coalesced global reads, one-time).
    for (int t = tid; t < NTOT * KD; t += 256) {
        int n = t >> 4, k = t & 15;
        vL[n * VSTRIDE + k] = v[t];
    }
    // sum_of_square collapses: sum_k sum_n e_n^2 v[n,k]^2 = sum_n e_n^2*vsq_n
    for (int n = tid; n < NTOT; n += 256) {
        const float* vr = v + n * KD;
        float s = 0.f;
#pragma unroll
        for (int k = 0; k < KD; ++k) s = fmaf(vr[k], vr[k], s);
        wvs[n] = make_float2(W[n], s);
    }
    __syncthreads();

    const int g = tid >> 4;  // row within block
    const int j = tid & 15;  // embedding element within field
    const int row = blockIdx.x * 16 + g;

    // Row indices (16-way broadcast within the group; 8B-aligned).
    int idx[NF];
    {
        const int2* xr = (const int2*)(X + row * NF);
#pragma unroll
        for (int i = 0; i < NF / 2; ++i) {
            int2 t2 = xr[i];
            idx[2 * i] = t2.x;
            idx[2 * i + 1] = t2.y;
        }
    }

    // Issue ALL 26 embedding-element gathers upfront (independent loads).
    // Each group-field: 16 lanes read 64 consecutive bytes -> coalesced.
    float e[NF];
#pragma unroll
    for (int f = 0; f < NF; ++f) {
        unsigned off =
            (unsigned)(f * VOCAB + idx[f]) * (unsigned)(EMB * 4) + (j << 2);
        e[f] = *(const float*)((const char*)tables + off);
    }

    float xv[KD];
#pragma unroll
    for (int k = 0; k < KD; ++k) xv[k] = 0.f;
    float lin = 0.f, sos = 0.f;

#pragma unroll
    for (int f = 0; f < NF; ++f) {
        const int n = f * EMB + j;
        const float4* vr = (const float4*)&vL[n * VSTRIDE];
        float4 v0 = vr[0], v1 = vr[1], v2 = vr[2], v3 = vr[3];
        const float ef = e[f];
        xv[0] = fmaf(ef, v0.x, xv[0]);
        xv[1] = fmaf(ef, v0.y, xv[1]);
        xv[2] = fmaf(ef, v0.z, xv[2]);
        xv[3] = fmaf(ef, v0.w, xv[3]);
        xv[4] = fmaf(ef, v1.x, xv[4]);
        xv[5] = fmaf(ef, v1.y, xv[5]);
        xv[6] = fmaf(ef, v1.z, xv[6]);
        xv[7] = fmaf(ef, v1.w, xv[7]);
        xv[8] = fmaf(ef, v2.x, xv[8]);
        xv[9] = fmaf(ef, v2.y, xv[9]);
        xv[10] = fmaf(ef, v2.z, xv[10]);
        xv[11] = fmaf(ef, v2.w, xv[11]);
        xv[12] = fmaf(ef, v3.x, xv[12]);
        xv[13] = fmaf(ef, v3.y, xv[13]);
        xv[14] = fmaf(ef, v3.z, xv[14]);
        xv[15] = fmaf(ef, v3.w, xv[15]);

        float2 w2 = wvs[n];
        lin = fmaf(ef, w2.x, lin);
        sos = fmaf(ef * ef, w2.y, sos);
    }

    // Vector butterfly: sum xv[k] partials across the 16 element-lanes.
#pragma unroll
    for (int m = 1; m < 16; m <<= 1) {
#pragma unroll
        for (int k = 0; k < KD; ++k) xv[k] += __shfl_xor(xv[k], m, 16);
    }

    float ss = 0.f;
#pragma unroll
    for (int k = 0; k < KD; ++k) ss = fmaf(xv[k], xv[k], ss);

    // Scalar butterfly for the per-lane lin/sos partials.
    float t = fmaf(-0.5f, sos, lin);
#pragma unroll
    for (int m = 1; m < 16; m <<= 1) t += __shfl_xor(t, m, 16);

    if (j == 0) {
        const float z = t + 0.5f * ss + bptr[0];
        out[row] = 1.0f / (1.0f + __expf(-z));
    }
}

// Inputs: X[int32 16384x26], tables[f32 26x100000x16], W[f32 416x1],
// b[f32 1], v[f32 416x16]. Output: f32 [16384].
extern "C" void kernel_launch(void* const* d_in, const int* in_sizes, int n_in,
                              void* d_out, int out_size, void* d_ws,
                              size_t ws_size, hipStream_t stream) {
    const int* X = (const int*)d_in[0];
    const float* tables = (const float*)d_in[1];
    const float* W = (const float*)d_in[2];
    const float* b = (const float*)d_in[3];
    const float* v = (const float*)d_in[4];
    float* out = (float*)d_out;

    fm_kernel<<<BATCH / 16, 256, 0, stream>>>(X, tables, W, b, v, out);
}

// Round 4
// 219.156 us; speedup vs baseline: 1.3062x; 1.0038x over previous
//
#include <hip/hip_runtime.h>
#include <hip/hip_bf16.h>
#include <math.h>

#define NF 26
#define VOCAB 100000
#define EMB 16
#define BATCH 16384
#define NTOT 416    // 26*16
#define NCHUNK 13   // 416 / 32 (MFMA K)
#define RPB 8       // real rows per wave (MFMA tile rows 8..15 duplicate 0..7)

typedef __attribute__((ext_vector_type(8))) short bf16x8;  // 8 bf16 (4 VGPRs)
typedef __attribute__((ext_vector_type(4))) float f32x4;   // MFMA C/D

__device__ __forceinline__ short2 cvt_pk(float a, float b) {
    union { __hip_bfloat162 h; short2 s; } u;
    u.h = __float22bfloat162_rn(make_float2(a, b));  // v_cvt_pk_bf16_f32
    return u.s;
}

__device__ __forceinline__ bf16x8 pack8(float4 a, float4 b) {
    short2 p0 = cvt_pk(a.x, a.y), p1 = cvt_pk(a.z, a.w);
    short2 p2 = cvt_pk(b.x, b.y), p3 = cvt_pk(b.z, b.w);
    bf16x8 r;
    r[0] = p0.x; r[1] = p0.y; r[2] = p1.x; r[3] = p1.y;
    r[4] = p2.x; r[5] = p2.y; r[6] = p3.x; r[7] = p3.y;
    return r;
}

// One wave per block; wave computes 8 batch rows via one 16x16 MFMA tile
// accumulated over 13 K=32 chunks. GEMM axes: M = batch rows (dup x2),
// K = 416 embedding dims, N = 16 factor dims.
// A[m=lane&15][k=quad*8+j] -> lane gathers 8 consecutive embedding floats.
// B[k=quad*8+j][n=lane&15] -> v[(chunk*32+quad*8+j)*16 + (lane&15)], in regs.
// C/D: col=lane&15, row=(lane>>4)*4+reg (m89/m91-verified layout).
__global__ __launch_bounds__(64, 2) void fm_kernel(
    const int* __restrict__ X, const float* __restrict__ tables,
    const float* __restrict__ W, const float* __restrict__ bptr,
    const float* __restrict__ v, float* __restrict__ out) {
    __shared__ float2 wvs[NTOT];  // {W[n], -0.5*sum_k v[n][k]^2}

    const int l = threadIdx.x;
    const int col = l & 15;       // A-row m / B-col n
    const int quad = l >> 4;
    const int halfsel = quad & 1; // which 8-float half of a field row
    const int fpar = quad >> 1;   // field parity this lane covers
    const int r = blockIdx.x * RPB + (col & 7);

    // --- 13 independent idx loads (this lane's 13 fields), issued upfront ---
    int idxv[NCHUNK];
    {
        const int* xr = X + r * NF + fpar;
#pragma unroll
        for (int c = 0; c < NCHUNK; ++c) idxv[c] = xr[2 * c];
    }

    // --- wv setup: lin - 0.5*sos = sum_n e*(W[n] + e*u[n]), u = -0.5*vsq ---
    for (int n = l; n < NTOT; n += 64) {
        const float4* vr = (const float4*)(v + n * 16);
        float4 a0 = vr[0], a1 = vr[1], a2 = vr[2], a3 = vr[3];
        float s = a0.x * a0.x;
        s = fmaf(a0.y, a0.y, s); s = fmaf(a0.z, a0.z, s); s = fmaf(a0.w, a0.w, s);
        s = fmaf(a1.x, a1.x, s); s = fmaf(a1.y, a1.y, s); s = fmaf(a1.z, a1.z, s);
        s = fmaf(a1.w, a1.w, s); s = fmaf(a2.x, a2.x, s); s = fmaf(a2.y, a2.y, s);
        s = fmaf(a2.z, a2.z, s); s = fmaf(a2.w, a2.w, s); s = fmaf(a3.x, a3.x, s);
        s = fmaf(a3.y, a3.y, s); s = fmaf(a3.z, a3.z, s); s = fmaf(a3.w, a3.w, s);
        wvs[n] = make_float2(W[n], -0.5f * s);
    }

    // --- B fragments: whole v in wave registers, one-time (L1/L2-resident) ---
    bf16x8 Bf[NCHUNK];
#pragma unroll
    for (int c = 0; c < NCHUNK; ++c) {
        const float* vp = v + (c * 32 + quad * 8) * 16 + col;
        float4 b0 = make_float4(vp[0], vp[16], vp[32], vp[48]);
        float4 b1 = make_float4(vp[64], vp[80], vp[96], vp[112]);
        Bf[c] = pack8(b0, b1);
    }

    __syncthreads();

    // --- all 26 embedding gathers issued upfront (depth-26 MLP) ---
    float4 g0[NCHUNK], g1[NCHUNK];
#pragma unroll
    for (int c = 0; c < NCHUNK; ++c) {
        const int f = 2 * c + fpar;
        const char* base = (const char*)tables +
                           (((unsigned)(f * VOCAB + idxv[c])) << 6) +
                           (halfsel << 5);
        g0[c] = *(const float4*)base;
        g1[c] = *(const float4*)(base + 16);
    }

    // --- main loop: t-partials (fp32) + A-convert + MFMA ---
    f32x4 acc = {0.f, 0.f, 0.f, 0.f};
    float tp = 0.f;
#pragma unroll
    for (int c = 0; c < NCHUNK; ++c) {
        float4 e0 = g0[c], e1 = g1[c];
        const float4* wp = (const float4*)&wvs[c * 32 + quad * 8];
        float4 w0 = wp[0], w1 = wp[1], w2 = wp[2], w3 = wp[3];
        tp = fmaf(e0.x, fmaf(e0.x, w0.y, w0.x), tp);
        tp = fmaf(e0.y, fmaf(e0.y, w0.w, w0.z), tp);
        tp = fmaf(e0.z, fmaf(e0.z, w1.y, w1.x), tp);
        tp = fmaf(e0.w, fmaf(e0.w, w1.w, w1.z), tp);
        tp = fmaf(e1.x, fmaf(e1.x, w2.y, w2.x), tp);
        tp = fmaf(e1.y, fmaf(e1.y, w2.w, w2.z), tp);
        tp = fmaf(e1.z, fmaf(e1.z, w3.y, w3.x), tp);
        tp = fmaf(e1.w, fmaf(e1.w, w3.w, w3.z), tp);
        acc = __builtin_amdgcn_mfma_f32_16x16x32_bf16(pack8(e0, e1), Bf[c],
                                                      acc, 0, 0, 0);
    }

    // --- reduce t = lin - 0.5*sos over the 4 quads -> t_full[m] in all lanes
    tp += __shfl_xor(tp, 16);
    tp += __shfl_xor(tp, 32);

    // --- S[row] = sum_k xv^2 : butterfly over the 16 n-lanes (C-layout cols)
    float s0 = acc[0] * acc[0], s1 = acc[1] * acc[1];
    float s2 = acc[2] * acc[2], s3 = acc[3] * acc[3];
#pragma unroll
    for (int mask = 1; mask < 16; mask <<= 1) {
        s0 += __shfl_xor(s0, mask);
        s1 += __shfl_xor(s1, mask);
        s2 += __shfl_xor(s2, mask);
        s3 += __shfl_xor(s3, mask);
    }

    // --- route t to the S holders: rows quad*4 + {0..3} live in lane quad*4+reg
    float t0 = __shfl(tp, quad * 4 + 0);
    float t1 = __shfl(tp, quad * 4 + 1);
    float t2 = __shfl(tp, quad * 4 + 2);
    float t3 = __shfl(tp, quad * 4 + 3);

    if (col == 0 && quad < 2) {  // rows 0..7 (quads 2,3 are duplicates)
        const float bb = bptr[0];
        float4 o;
        o.x = 1.f / (1.f + __expf(-(t0 + 0.5f * s0 + bb)));
        o.y = 1.f / (1.f + __expf(-(t1 + 0.5f * s1 + bb)));
        o.z = 1.f / (1.f + __expf(-(t2 + 0.5f * s2 + bb)));
        o.w = 1.f / (1.f + __expf(-(t3 + 0.5f * s3 + bb)));
        *(float4*)(out + blockIdx.x * RPB + quad * 4) = o;
    }
}

// Inputs: X[int32 16384x26], tables[f32 26x100000x16], W[f32 416x1],
// b[f32 1], v[f32 416x16]. Output: f32 [16384].
extern "C" void kernel_launch(void* const* d_in, const int* in_sizes, int n_in,
                              void* d_out, int out_size, void* d_ws,
                              size_t ws_size, hipStream_t stream) {
    const int* X = (const int*)d_in[0];
    const float* tables = (const float*)d_in[1];
    const float* W = (const float*)d_in[2];
    const float* b = (const float*)d_in[3];
    const float* v = (const float*)d_in[4];
    float* out = (float*)d_out;

    // 2048 single-wave blocks = exactly 2 waves/SIMD chip-wide.
    fm_kernel<<<BATCH / RPB, 64, 0, stream>>>(X, tables, W, b, v, out);
}

// Round 5
// 215.821 us; speedup vs baseline: 1.3264x; 1.0155x over previous
//
#include <hip/hip_runtime.h>
#include <hip/hip_bf16.h>
#include <math.h>

#define NF 26
#define VOCAB 100000
#define EMB 16
#define BATCH 16384
#define NTOT 416    // 26*16
#define NCHUNK 13   // 416 / 32 (MFMA K)
#define RPB 8       // real rows per wave (MFMA tile rows 8..15 duplicate 0..7)

typedef __attribute__((ext_vector_type(8))) short bf16x8;  // 8 bf16 (4 VGPRs)
typedef __attribute__((ext_vector_type(4))) float f32x4;   // MFMA C/D
typedef __attribute__((ext_vector_type(4))) float vf4;     // nt-loadable float4

__device__ __forceinline__ short2 cvt_pk(float a, float b) {
    union { __hip_bfloat162 h; short2 s; } u;
    u.h = __float22bfloat162_rn(make_float2(a, b));  // v_cvt_pk_bf16_f32
    return u.s;
}

__device__ __forceinline__ bf16x8 pack8(vf4 a, vf4 b) {
    short2 p0 = cvt_pk(a.x, a.y), p1 = cvt_pk(a.z, a.w);
    short2 p2 = cvt_pk(b.x, b.y), p3 = cvt_pk(b.z, b.w);
    bf16x8 r;
    r[0] = p0.x; r[1] = p0.y; r[2] = p1.x; r[3] = p1.y;
    r[4] = p2.x; r[5] = p2.y; r[6] = p3.x; r[7] = p3.y;
    return r;
}

// One wave per block; wave computes 8 batch rows via one 16x16 MFMA tile over
// 13 K=32 chunks. Gathers are NONTEMPORAL (L1 bypass: streaming, 92%-unique
// data; frees L1 MSHRs for more outstanding misses) and issued before the
// v/W staging so staging latency hides inside the gather round-trip.
__global__ __launch_bounds__(64, 2) void fm_kernel(
    const int* __restrict__ X, const float* __restrict__ tables,
    const float* __restrict__ W, const float* __restrict__ bptr,
    const float* __restrict__ v, float* __restrict__ out) {
    __shared__ float2 wvs[NTOT];  // {W[n], -0.5*sum_k v[n][k]^2}

    const int l = threadIdx.x;
    const int col = l & 15;       // A-row m / B-col n
    const int quad = l >> 4;
    const int halfsel = quad & 1; // which 8-float half of a field row
    const int fpar = quad >> 1;   // field parity this lane covers
    const int r = blockIdx.x * RPB + (col & 7);

    // --- 13 independent idx loads (this lane's 13 fields), nt, upfront ---
    int idxv[NCHUNK];
    {
        const int* xr = X + r * NF + fpar;
#pragma unroll
        for (int c = 0; c < NCHUNK; ++c)
            idxv[c] = __builtin_nontemporal_load(xr + 2 * c);
    }

    // --- all 26 embedding gathers issued IMMEDIATELY (depth-26 MLP, nt) ---
    vf4 g0[NCHUNK], g1[NCHUNK];
#pragma unroll
    for (int c = 0; c < NCHUNK; ++c) {
        const int f = 2 * c + fpar;
        const char* base = (const char*)tables +
                           (((unsigned)(f * VOCAB + idxv[c])) << 6) +
                           (halfsel << 5);
        g0[c] = __builtin_nontemporal_load((const vf4*)base);
        g1[c] = __builtin_nontemporal_load((const vf4*)(base + 16));
    }

    // --- wv staging (overlaps gather latency): lin - 0.5*sos =
    //     sum_n e*(W[n] + e*u[n]), u = -0.5*sum_k v[n][k]^2 ---
    for (int n = l; n < NTOT; n += 64) {
        const float4* vr = (const float4*)(v + n * 16);
        float4 a0 = vr[0], a1 = vr[1], a2 = vr[2], a3 = vr[3];
        float s = a0.x * a0.x;
        s = fmaf(a0.y, a0.y, s); s = fmaf(a0.z, a0.z, s); s = fmaf(a0.w, a0.w, s);
        s = fmaf(a1.x, a1.x, s); s = fmaf(a1.y, a1.y, s); s = fmaf(a1.z, a1.z, s);
        s = fmaf(a1.w, a1.w, s); s = fmaf(a2.x, a2.x, s); s = fmaf(a2.y, a2.y, s);
        s = fmaf(a2.z, a2.z, s); s = fmaf(a2.w, a2.w, s); s = fmaf(a3.x, a3.x, s);
        s = fmaf(a3.y, a3.y, s); s = fmaf(a3.z, a3.z, s); s = fmaf(a3.w, a3.w, s);
        wvs[n] = make_float2(W[n], -0.5f * s);
    }

    // --- B fragments: whole v in wave registers (cached loads, reused) ---
    bf16x8 Bf[NCHUNK];
#pragma unroll
    for (int c = 0; c < NCHUNK; ++c) {
        const float* vp = v + (c * 32 + quad * 8) * 16 + col;
        vf4 b0 = {vp[0], vp[16], vp[32], vp[48]};
        vf4 b1 = {vp[64], vp[80], vp[96], vp[112]};
        Bf[c] = pack8(b0, b1);
    }

    __syncthreads();

    // --- main loop: t-partials (fp32) + A-convert + MFMA ---
    f32x4 acc = {0.f, 0.f, 0.f, 0.f};
    float tp = 0.f;
#pragma unroll
    for (int c = 0; c < NCHUNK; ++c) {
        vf4 e0 = g0[c], e1 = g1[c];
        const float4* wp = (const float4*)&wvs[c * 32 + quad * 8];
        float4 w0 = wp[0], w1 = wp[1], w2 = wp[2], w3 = wp[3];
        tp = fmaf(e0.x, fmaf(e0.x, w0.y, w0.x), tp);
        tp = fmaf(e0.y, fmaf(e0.y, w0.w, w0.z), tp);
        tp = fmaf(e0.z, fmaf(e0.z, w1.y, w1.x), tp);
        tp = fmaf(e0.w, fmaf(e0.w, w1.w, w1.z), tp);
        tp = fmaf(e1.x, fmaf(e1.x, w2.y, w2.x), tp);
        tp = fmaf(e1.y, fmaf(e1.y, w2.w, w2.z), tp);
        tp = fmaf(e1.z, fmaf(e1.z, w3.y, w3.x), tp);
        tp = fmaf(e1.w, fmaf(e1.w, w3.w, w3.z), tp);
        acc = __builtin_amdgcn_mfma_f32_16x16x32_bf16(pack8(e0, e1), Bf[c],
                                                      acc, 0, 0, 0);
    }

    // --- reduce t = lin - 0.5*sos over the 4 quads ---
    tp += __shfl_xor(tp, 16);
    tp += __shfl_xor(tp, 32);

    // --- S[row] = sum_k xv^2 : butterfly over the 16 n-lanes (C-layout) ---
    float s0 = acc[0] * acc[0], s1 = acc[1] * acc[1];
    float s2 = acc[2] * acc[2], s3 = acc[3] * acc[3];
#pragma unroll
    for (int mask = 1; mask < 16; mask <<= 1) {
        s0 += __shfl_xor(s0, mask);
        s1 += __shfl_xor(s1, mask);
        s2 += __shfl_xor(s2, mask);
        s3 += __shfl_xor(s3, mask);
    }

    // --- route t to the S holders: row quad*4+reg lives in lane quad*4+reg
    float t0 = __shfl(tp, quad * 4 + 0);
    float t1 = __shfl(tp, quad * 4 + 1);
    float t2 = __shfl(tp, quad * 4 + 2);
    float t3 = __shfl(tp, quad * 4 + 3);

    if (col == 0 && quad < 2) {  // rows 0..7 (quads 2,3 are duplicates)
        const float bb = bptr[0];
        float4 o;
        o.x = 1.f / (1.f + __expf(-(t0 + 0.5f * s0 + bb)));
        o.y = 1.f / (1.f + __expf(-(t1 + 0.5f * s1 + bb)));
        o.z = 1.f / (1.f + __expf(-(t2 + 0.5f * s2 + bb)));
        o.w = 1.f / (1.f + __expf(-(t3 + 0.5f * s3 + bb)));
        *(float4*)(out + blockIdx.x * RPB + quad * 4) = o;
    }
}

// Inputs: X[int32 16384x26], tables[f32 26x100000x16], W[f32 416x1],
// b[f32 1], v[f32 416x16]. Output: f32 [16384].
extern "C" void kernel_launch(void* const* d_in, const int* in_sizes, int n_in,
                              void* d_out, int out_size, void* d_ws,
                              size_t ws_size, hipStream_t stream) {
    const int* X = (const int*)d_in[0];
    const float* tables = (const float*)d_in[1];
    const float* W = (const float*)d_in[2];
    const float* b = (const float*)d_in[3];
    const float* v = (const float*)d_in[4];
    float* out = (float*)d_out;

    // 2048 single-wave blocks = 2 waves/SIMD chip-wide.
    fm_kernel<<<BATCH / RPB, 64, 0, stream>>>(X, tables, W, b, v, out);
}

// Round 7
// 213.690 us; speedup vs baseline: 1.3396x; 1.0100x over previous
//
#include <hip/hip_runtime.h>
#include <hip/hip_bf16.h>
#include <math.h>

#define NF 26
#define VOCAB 100000
#define EMB 16
#define BATCH 16384
#define NTOT 416    // 26*16
#define NCHUNK 13   // 416 / 32 (MFMA K)
#define RPB 8       // real rows per wave (MFMA tile rows 8..15 duplicate 0..7)

typedef __attribute__((ext_vector_type(8))) short bf16x8;  // 8 bf16 (4 VGPRs)
typedef __attribute__((ext_vector_type(4))) float f32x4;   // MFMA C/D
typedef __attribute__((ext_vector_type(4))) float vf4;

__device__ __forceinline__ short2 cvt_pk(float a, float b) {
    union { __hip_bfloat162 h; short2 s; } u;
    u.h = __float22bfloat162_rn(make_float2(a, b));  // v_cvt_pk_bf16_f32
    return u.s;
}

__device__ __forceinline__ bf16x8 pack8(vf4 a, vf4 b) {
    short2 p0 = cvt_pk(a.x, a.y), p1 = cvt_pk(a.z, a.w);
    short2 p2 = cvt_pk(b.x, b.y), p3 = cvt_pk(b.z, b.w);
    bf16x8 r;
    r[0] = p0.x; r[1] = p0.y; r[2] = p1.x; r[3] = p1.y;
    r[4] = p2.x; r[5] = p2.y; r[6] = p3.x; r[7] = p3.y;
    return r;
}

// One wave/block; 8 batch rows via one 16x16 MFMA tile over 13 K=32 chunks.
// Gather: each 64 B (row,field) line covered by ONE instruction (13 VMEM
// gathers/wave, 208 unique line-touches -- the R6 request-halving win).
// Cross-lane A-fragment exchange goes through LDS + __syncthreads (R6's
// shfl_xor reassembly showed sporadic post-timing corruption; memory +
// barrier is the bulletproof ordering).
__global__ __launch_bounds__(64, 2) void fm_kernel(
    const int* __restrict__ X, const float* __restrict__ tables,
    const float* __restrict__ W, const float* __restrict__ bptr,
    const float* __restrict__ v, float* __restrict__ out) {
    __shared__ vf4 exA[NCHUNK][64];  // 13312 B: gather exchange buffer
    __shared__ float2 wvs[NTOT];     // 3328 B: {W[n], -0.5*sum_k v[n][k]^2}

    const int l = threadIdx.x;
    const int col = l & 15;        // A-row m (pair col/col+8) / B-col n
    const int quad = l >> 4;
    const int hi = (col >> 3) & 1; // which 16B segment of the 32B half
    const int hsel = quad & 1;     // which 32B half of the field row
    const int fpar = quad >> 1;    // field parity this lane covers
    const int r = blockIdx.x * RPB + (col & 7);

    // --- 13 independent idx loads (strided dwords share cache lines) ---
    int idxv[NCHUNK];
    {
        const int* xr = X + r * NF + fpar;
#pragma unroll
        for (int c = 0; c < NCHUNK; ++c) idxv[c] = xr[2 * c];
    }

    // --- 13 gathers, one 16B segment per lane, issued upfront (nt) ---
    vf4 gown[NCHUNK];
#pragma unroll
    for (int c = 0; c < NCHUNK; ++c) {
        const int f = 2 * c + fpar;
        const int seg = hsel * 2 + hi;  // 16B segment within the 64B row
        const char* base = (const char*)tables +
                           (((unsigned)(f * VOCAB + idxv[c])) << 6) +
                           (seg << 4);
        gown[c] = __builtin_nontemporal_load((const vf4*)base);
    }

    // --- wv staging (overlaps gather latency): lin - 0.5*sos =
    //     sum_n e*(W[n] + e*u[n]), u = -0.5*sum_k v[n][k]^2 ---
    for (int n = l; n < NTOT; n += 64) {
        const float4* vr = (const float4*)(v + n * 16);
        float4 a0 = vr[0], a1 = vr[1], a2 = vr[2], a3 = vr[3];
        float s = a0.x * a0.x;
        s = fmaf(a0.y, a0.y, s); s = fmaf(a0.z, a0.z, s); s = fmaf(a0.w, a0.w, s);
        s = fmaf(a1.x, a1.x, s); s = fmaf(a1.y, a1.y, s); s = fmaf(a1.z, a1.z, s);
        s = fmaf(a1.w, a1.w, s); s = fmaf(a2.x, a2.x, s); s = fmaf(a2.y, a2.y, s);
        s = fmaf(a2.z, a2.z, s); s = fmaf(a2.w, a2.w, s); s = fmaf(a3.x, a3.x, s);
        s = fmaf(a3.y, a3.y, s); s = fmaf(a3.z, a3.z, s); s = fmaf(a3.w, a3.w, s);
        wvs[n] = make_float2(W[n], -0.5f * s);
    }

    // --- B fragments: whole v in wave registers (cached loads, reused) ---
    bf16x8 Bf[NCHUNK];
#pragma unroll
    for (int c = 0; c < NCHUNK; ++c) {
        const float* vp = v + (c * 32 + quad * 8) * 16 + col;
        vf4 b0 = {vp[0], vp[16], vp[32], vp[48]};
        vf4 b1 = {vp[64], vp[80], vp[96], vp[112]};
        Bf[c] = pack8(b0, b1);
    }

    // --- park gathers in LDS for the cross-lane fragment exchange ---
#pragma unroll
    for (int c = 0; c < NCHUNK; ++c) exA[c][l] = gown[c];

    __syncthreads();

    // --- main loop: fragment reads from LDS + t-partials + MFMA ---
    // Owner algebra: elements n = c*32 + quad*8 + {0..7} of row m live in
    // lanes quad*16 + (m&7) (first 4, hi=0) and +8 (last 4, hi=1).
    f32x4 acc = {0.f, 0.f, 0.f, 0.f};
    float tp = 0.f;
    const int ebase = quad * 16 + (col & 7);
#pragma unroll
    for (int c = 0; c < NCHUNK; ++c) {
        vf4 e0 = exA[c][ebase];
        vf4 e1 = exA[c][ebase + 8];

        const float4* wp = (const float4*)&wvs[c * 32 + quad * 8];
        float4 w0 = wp[0], w1 = wp[1], w2 = wp[2], w3 = wp[3];
        tp = fmaf(e0.x, fmaf(e0.x, w0.y, w0.x), tp);
        tp = fmaf(e0.y, fmaf(e0.y, w0.w, w0.z), tp);
        tp = fmaf(e0.z, fmaf(e0.z, w1.y, w1.x), tp);
        tp = fmaf(e0.w, fmaf(e0.w, w1.w, w1.z), tp);
        tp = fmaf(e1.x, fmaf(e1.x, w2.y, w2.x), tp);
        tp = fmaf(e1.y, fmaf(e1.y, w2.w, w2.z), tp);
        tp = fmaf(e1.z, fmaf(e1.z, w3.y, w3.x), tp);
        tp = fmaf(e1.w, fmaf(e1.w, w3.w, w3.z), tp);
        acc = __builtin_amdgcn_mfma_f32_16x16x32_bf16(pack8(e0, e1), Bf[c],
                                                      acc, 0, 0, 0);
    }

    // --- reduce t = lin - 0.5*sos over the 4 quads ---
    tp += __shfl_xor(tp, 16);
    tp += __shfl_xor(tp, 32);

    // --- S[row] = sum_k xv^2 : butterfly over the 16 n-lanes (C-layout) ---
    float s0 = acc[0] * acc[0], s1 = acc[1] * acc[1];
    float s2 = acc[2] * acc[2], s3 = acc[3] * acc[3];
#pragma unroll
    for (int mask = 1; mask < 16; mask <<= 1) {
        s0 += __shfl_xor(s0, mask);
        s1 += __shfl_xor(s1, mask);
        s2 += __shfl_xor(s2, mask);
        s3 += __shfl_xor(s3, mask);
    }

    // --- route t to the S holders: row quad*4+reg lives in lane quad*4+reg
    float t0 = __shfl(tp, quad * 4 + 0);
    float t1 = __shfl(tp, quad * 4 + 1);
    float t2 = __shfl(tp, quad * 4 + 2);
    float t3 = __shfl(tp, quad * 4 + 3);

    if (col == 0 && quad < 2) {  // rows 0..7 (quads 2,3 are duplicates)
        const float bb = bptr[0];
        float4 o;
        o.x = 1.f / (1.f + __expf(-(t0 + 0.5f * s0 + bb)));
        o.y = 1.f / (1.f + __expf(-(t1 + 0.5f * s1 + bb)));
        o.z = 1.f / (1.f + __expf(-(t2 + 0.5f * s2 + bb)));
        o.w = 1.f / (1.f + __expf(-(t3 + 0.5f * s3 + bb)));
        *(float4*)(out + blockIdx.x * RPB + quad * 4) = o;
    }
}

// Inputs: X[int32 16384x26], tables[f32 26x100000x16], W[f32 416x1],
// b[f32 1], v[f32 416x16]. Output: f32 [16384].
extern "C" void kernel_launch(void* const* d_in, const int* in_sizes, int n_in,
                              void* d_out, int out_size, void* d_ws,
                              size_t ws_size, hipStream_t stream) {
    const int* X = (const int*)d_in[0];
    const float* tables = (const float*)d_in[1];
    const float* W = (const float*)d_in[2];
    const float* b = (const float*)d_in[3];
    const float* v = (const float*)d_in[4];
    float* out = (float*)d_out;

    // 2048 single-wave blocks = 8 blocks/CU (LDS allows 9).
    fm_kernel<<<BATCH / RPB, 64, 0, stream>>>(X, tables, W, b, v, out);
}